// Round 1
// baseline (5130.134 us; speedup 1.0000x reference)
//
#include <hip/hip_runtime.h>

#define NN 50000
#define NE 800000

__device__ __forceinline__ float silu_f(float v) {
    return v / (1.0f + __expf(-v));
}

// ---------------- prep: d2 per edge, degree per node ----------------
__global__ __launch_bounds__(256) void egnn_prep(
    const int* __restrict__ src, const int* __restrict__ dst,
    const float* __restrict__ pos,
    float* __restrict__ d2, float* __restrict__ deg)
{
    int e = blockIdx.x * 256 + threadIdx.x;
    if (e >= NE) return;
    int s = src[e], d = dst[e];
    float rx = pos[3*d+0] - pos[3*s+0];
    float ry = pos[3*d+1] - pos[3*s+1];
    float rz = pos[3*d+2] - pos[3*s+2];
    d2[e] = rx*rx + ry*ry + rz*rz;
    atomicAdd(&deg[d], 1.0f);
}

// ---------------- edge MLP + scatter (tile of 64 edges per block) ----------------
// 4 waves per block; wave w owns output channels [w*16, w*16+16).
template<bool POS>
__global__ __launch_bounds__(256) void egnn_edge(
    const float* __restrict__ x, const float* __restrict__ d2,
    const int* __restrict__ src, const int* __restrict__ dst,
    const float* __restrict__ pos,
    const float* __restrict__ We1, const float* __restrict__ be1,
    const float* __restrict__ We2, const float* __restrict__ be2,
    const float* __restrict__ Wp1, const float* __restrict__ bp1,
    const float* __restrict__ Wp2, const float* __restrict__ bp2,
    float* __restrict__ agg, float* __restrict__ dpos, int layer)
{
    __shared__ float sIn[64 * 65];   // staged inputs (dst half, then src half, then m2)
    __shared__ float sM1[64 * 65];   // hidden activations
    __shared__ int   sSrc[64];
    __shared__ int   sDst[64];
    __shared__ float sD2[64];
    __shared__ float sC[64];

    const int t    = threadIdx.x;
    const int w    = t >> 6;
    const int lane = t & 63;
    const int base = blockIdx.x * 64;

    if (t < 64) {
        sSrc[t] = src[base + t];
        sDst[t] = dst[base + t];
        sD2[t]  = d2[base + t];
        if (POS) sC[t] = bp2[layer];
    }
    __syncthreads();

    // ---- stage x[dst] rows into sIn ----
    #pragma unroll
    for (int i = 0; i < 4; ++i) {
        int e = (t >> 4) + i * 16;
        int c = t & 15;
        const float4 v = *reinterpret_cast<const float4*>(&x[(size_t)sDst[e] * 64 + c * 4]);
        float* p = &sIn[e * 65 + c * 4];
        p[0] = v.x; p[1] = v.y; p[2] = v.z; p[3] = v.w;
    }
    __syncthreads();

    // ---- GEMM1, k = 0..63 (x[dst] part) ----
    float acc[16];
    {
        const float* b = &be1[layer * 64 + w * 16];
        #pragma unroll
        for (int hh = 0; hh < 16; ++hh) acc[hh] = b[hh];
    }
    const float* W1 = &We1[(size_t)layer * 129 * 64 + w * 16];
    for (int k = 0; k < 64; ++k) {
        float inv = sIn[lane * 65 + k];
        const float* wr = W1 + k * 64;
        #pragma unroll
        for (int hh = 0; hh < 16; ++hh) acc[hh] = fmaf(inv, wr[hh], acc[hh]);
    }
    __syncthreads();

    // ---- stage x[src] rows (overwrite sIn) ----
    #pragma unroll
    for (int i = 0; i < 4; ++i) {
        int e = (t >> 4) + i * 16;
        int c = t & 15;
        const float4 v = *reinterpret_cast<const float4*>(&x[(size_t)sSrc[e] * 64 + c * 4]);
        float* p = &sIn[e * 65 + c * 4];
        p[0] = v.x; p[1] = v.y; p[2] = v.z; p[3] = v.w;
    }
    __syncthreads();

    // ---- GEMM1, k = 64..127 (x[src] part) + d2 term ----
    for (int k = 0; k < 64; ++k) {
        float inv = sIn[lane * 65 + k];
        const float* wr = W1 + (64 + k) * 64;
        #pragma unroll
        for (int hh = 0; hh < 16; ++hh) acc[hh] = fmaf(inv, wr[hh], acc[hh]);
    }
    {
        float dv = sD2[lane];
        const float* wr = W1 + 128 * 64;
        #pragma unroll
        for (int hh = 0; hh < 16; ++hh) acc[hh] = fmaf(dv, wr[hh], acc[hh]);
    }
    #pragma unroll
    for (int hh = 0; hh < 16; ++hh) acc[hh] = silu_f(acc[hh]);
    #pragma unroll
    for (int hh = 0; hh < 16; ++hh) sM1[lane * 65 + w * 16 + hh] = acc[hh];
    __syncthreads();

    // ---- GEMM2 (64 -> 64) ----
    float m2[16];
    {
        const float* b = &be2[layer * 64 + w * 16];
        #pragma unroll
        for (int hh = 0; hh < 16; ++hh) m2[hh] = b[hh];
    }
    const float* W2 = &We2[(size_t)layer * 64 * 64 + w * 16];
    for (int k = 0; k < 64; ++k) {
        float inv = sM1[lane * 65 + k];
        const float* wr = W2 + k * 64;
        #pragma unroll
        for (int hh = 0; hh < 16; ++hh) m2[hh] = fmaf(inv, wr[hh], m2[hh]);
    }
    #pragma unroll
    for (int hh = 0; hh < 16; ++hh) m2[hh] = silu_f(m2[hh]);
    // stash m2 in sIn (sIn reads all completed before previous barrier)
    #pragma unroll
    for (int hh = 0; hh < 16; ++hh) sIn[lane * 65 + w * 16 + hh] = m2[hh];
    __syncthreads();

    if (POS) {
        // p1 = silu(m2 @ Wp1 + bp1); c = p1 @ Wp2 + bp2  (only last layer matters)
        float p1[16];
        {
            const float* b = &bp1[layer * 64 + w * 16];
            #pragma unroll
            for (int hh = 0; hh < 16; ++hh) p1[hh] = b[hh];
        }
        const float* P1 = &Wp1[(size_t)layer * 64 * 64 + w * 16];
        for (int k = 0; k < 64; ++k) {
            float mv = sIn[lane * 65 + k];
            const float* wr = P1 + k * 64;
            #pragma unroll
            for (int hh = 0; hh < 16; ++hh) p1[hh] = fmaf(mv, wr[hh], p1[hh]);
        }
        float part = 0.0f;
        {
            const float* P2 = &Wp2[layer * 64 + w * 16];
            #pragma unroll
            for (int hh = 0; hh < 16; ++hh) part += silu_f(p1[hh]) * P2[hh];
        }
        atomicAdd(&sC[lane], part);
        __syncthreads();
        if (w == 0) {
            float c = sC[lane];
            int d = sDst[lane], s = sSrc[lane];
            float rx = pos[3*d+0] - pos[3*s+0];
            float ry = pos[3*d+1] - pos[3*s+1];
            float rz = pos[3*d+2] - pos[3*s+2];
            atomicAdd(&dpos[3*(size_t)d+0], rx * c);
            atomicAdd(&dpos[3*(size_t)d+1], ry * c);
            atomicAdd(&dpos[3*(size_t)d+2], rz * c);
        }
    }

    // ---- scatter m2 into agg (coalesced atomics: 64 lanes = 64 consecutive channels) ----
    #pragma unroll 1
    for (int i = 0; i < 16; ++i) {
        int e = w * 16 + i;
        atomicAdd(&agg[(size_t)sDst[e] * 64 + lane], sIn[e * 65 + lane]);
    }
}

// ---------------- node MLP (tile of 64 nodes per block) ----------------
__global__ __launch_bounds__(256) void egnn_node(
    const float* __restrict__ x, const float* __restrict__ agg,
    const float* __restrict__ Wn1, const float* __restrict__ bn1,
    const float* __restrict__ Wn2, const float* __restrict__ bn2,
    float* __restrict__ xout, int layer)
{
    __shared__ float sX[64 * 65];
    __shared__ float sA[64 * 65];

    const int t    = threadIdx.x;
    const int w    = t >> 6;
    const int lane = t & 63;
    const int base = blockIdx.x * 64;
    const int nval = (NN - base < 64) ? (NN - base) : 64;

    #pragma unroll
    for (int i = 0; i < 4; ++i) {
        int idx = i * 256 + t;
        int e = idx >> 4, c = idx & 15;
        if (e < nval) {
            const float4 vx = *reinterpret_cast<const float4*>(&x[(size_t)(base + e) * 64 + c * 4]);
            const float4 va = *reinterpret_cast<const float4*>(&agg[(size_t)(base + e) * 64 + c * 4]);
            float* px = &sX[e * 65 + c * 4];
            float* pa = &sA[e * 65 + c * 4];
            px[0]=vx.x; px[1]=vx.y; px[2]=vx.z; px[3]=vx.w;
            pa[0]=va.x; pa[1]=va.y; pa[2]=va.z; pa[3]=va.w;
        }
    }
    __syncthreads();

    float acc[16];
    {
        const float* b = &bn1[layer * 64 + w * 16];
        #pragma unroll
        for (int hh = 0; hh < 16; ++hh) acc[hh] = b[hh];
    }
    const float* W1 = &Wn1[(size_t)layer * 128 * 64 + w * 16];
    for (int k = 0; k < 64; ++k) {
        float inv = sX[lane * 65 + k];
        const float* wr = W1 + k * 64;
        #pragma unroll
        for (int hh = 0; hh < 16; ++hh) acc[hh] = fmaf(inv, wr[hh], acc[hh]);
    }
    for (int k = 0; k < 64; ++k) {
        float inv = sA[lane * 65 + k];
        const float* wr = W1 + (64 + k) * 64;
        #pragma unroll
        for (int hh = 0; hh < 16; ++hh) acc[hh] = fmaf(inv, wr[hh], acc[hh]);
    }
    #pragma unroll
    for (int hh = 0; hh < 16; ++hh) acc[hh] = silu_f(acc[hh]);
    __syncthreads();          // all waves done reading sA
    #pragma unroll
    for (int hh = 0; hh < 16; ++hh) sA[lane * 65 + w * 16 + hh] = acc[hh];
    __syncthreads();

    float o[16];
    {
        const float* b = &bn2[layer * 64 + w * 16];
        #pragma unroll
        for (int hh = 0; hh < 16; ++hh) o[hh] = b[hh];
    }
    const float* W2 = &Wn2[(size_t)layer * 64 * 64 + w * 16];
    for (int k = 0; k < 64; ++k) {
        float inv = sA[lane * 65 + k];
        const float* wr = W2 + k * 64;
        #pragma unroll
        for (int hh = 0; hh < 16; ++hh) o[hh] = fmaf(inv, wr[hh], o[hh]);
    }
    // stage to sX (all waves long done reading sX) then coalesced store
    #pragma unroll
    for (int hh = 0; hh < 16; ++hh) sX[lane * 65 + w * 16 + hh] = o[hh];
    __syncthreads();
    #pragma unroll
    for (int i = 0; i < 4; ++i) {
        int idx = i * 256 + t;
        int e = idx >> 4, c = idx & 15;
        if (e < nval) {
            float4 v;
            const float* p = &sX[e * 65 + c * 4];
            v.x = p[0]; v.y = p[1]; v.z = p[2]; v.w = p[3];
            *reinterpret_cast<float4*>(&xout[(size_t)(base + e) * 64 + c * 4]) = v;
        }
    }
}

// ---------------- finalize positions ----------------
__global__ __launch_bounds__(256) void egnn_final(
    const float* __restrict__ pos, const float* __restrict__ dpos,
    const float* __restrict__ deg, const float* __restrict__ logit,
    float* __restrict__ pos_out)
{
    int i = blockIdx.x * 256 + threadIdx.x;
    if (i >= NN * 3) return;
    int node = i / 3;
    float dg = fmaxf(deg[node], 1.0f);
    float sig = 1.0f / (1.0f + __expf(-logit[0]));
    float upd = (dpos[i] / dg) * sig;
    upd = fminf(fmaxf(upd, -5.0f), 5.0f);
    float p = pos[i] + upd;
    pos_out[i] = fminf(fmaxf(p, -500.0f), 500.0f);
}

extern "C" void kernel_launch(void* const* d_in, const int* in_sizes, int n_in,
                              void* d_out, int out_size, void* d_ws, size_t ws_size,
                              hipStream_t stream)
{
    const float* x0    = (const float*)d_in[0];
    const float* pos   = (const float*)d_in[1];
    const int*   src   = (const int*)d_in[2];
    const int*   dst   = src + NE;
    const float* We1   = (const float*)d_in[3];
    const float* be1   = (const float*)d_in[4];
    const float* We2   = (const float*)d_in[5];
    const float* be2   = (const float*)d_in[6];
    const float* Wn1   = (const float*)d_in[7];
    const float* bn1   = (const float*)d_in[8];
    const float* Wn2   = (const float*)d_in[9];
    const float* bn2   = (const float*)d_in[10];
    const float* Wp1   = (const float*)d_in[11];
    const float* bp1   = (const float*)d_in[12];
    const float* Wp2   = (const float*)d_in[13];
    const float* bp2   = (const float*)d_in[14];
    const float* logit = (const float*)d_in[15];

    float* xout    = (float*)d_out;                 // [NN,64]
    float* pos_out = xout + (size_t)NN * 64;        // [NN,3]

    float* ws  = (float*)d_ws;
    float* xA  = ws;  ws += (size_t)NN * 64;
    float* agg = ws;  ws += (size_t)NN * 64;
    float* d2  = ws;  ws += NE;
    float* deg = ws;  ws += NN;
    float* dpos= ws;  ws += (size_t)NN * 3;

    hipMemsetAsync(deg, 0, NN * sizeof(float), stream);
    hipMemsetAsync(dpos, 0, (size_t)NN * 3 * sizeof(float), stream);
    egnn_prep<<<NE / 256, 256, 0, stream>>>(src, dst, pos, d2, deg);

    const float* xin = x0;
    for (int l = 0; l < 4; ++l) {
        hipMemsetAsync(agg, 0, (size_t)NN * 64 * sizeof(float), stream);
        if (l == 3) {
            egnn_edge<true><<<NE / 64, 256, 0, stream>>>(
                xin, d2, src, dst, pos, We1, be1, We2, be2,
                Wp1, bp1, Wp2, bp2, agg, dpos, l);
        } else {
            egnn_edge<false><<<NE / 64, 256, 0, stream>>>(
                xin, d2, src, dst, pos, We1, be1, We2, be2,
                Wp1, bp1, Wp2, bp2, agg, dpos, l);
        }
        float* xo = (l % 2 == 0) ? xA : xout;       // l0->xA, l1->xout, l2->xA, l3->xout
        egnn_node<<<(NN + 63) / 64, 256, 0, stream>>>(xin, agg, Wn1, bn1, Wn2, bn2, xo, l);
        xin = xo;
    }
    egnn_final<<<(NN * 3 + 255) / 256, 256, 0, stream>>>(pos, dpos, deg, logit, pos_out);
}

// Round 2
// 2499.664 us; speedup vs baseline: 2.0523x; 2.0523x over previous
//
#include <hip/hip_runtime.h>

#define NN 50000
#define NE 800000

__device__ __forceinline__ float silu_f(float v) {
    return v / (1.0f + __expf(-v));
}

// ---------------- prep: d2 per edge, degree per node ----------------
__global__ __launch_bounds__(256) void egnn_prep(
    const int* __restrict__ src, const int* __restrict__ dst,
    const float* __restrict__ pos,
    float* __restrict__ d2, float* __restrict__ deg)
{
    int e = blockIdx.x * 256 + threadIdx.x;
    if (e >= NE) return;
    int s = src[e], d = dst[e];
    float rx = pos[3*d+0] - pos[3*s+0];
    float ry = pos[3*d+1] - pos[3*s+1];
    float rz = pos[3*d+2] - pos[3*s+2];
    d2[e] = rx*rx + ry*ry + rz*rz;
    atomicAdd(&deg[d], 1.0f);
}

// ---------------- edge MLP + scatter (tile of 64 edges per block) ----------------
// 4 waves per block; wave w owns output channels [w*16, w*16+16).
// All weight/bias pointers are made wave-uniform via readfirstlane so the
// backend emits s_load (scalar cache) instead of redundant vector loads.
template<bool POS>
__global__ __launch_bounds__(256) void egnn_edge(
    const float* __restrict__ x, const float* __restrict__ d2,
    const int* __restrict__ src, const int* __restrict__ dst,
    const float* __restrict__ pos,
    const float* __restrict__ We1, const float* __restrict__ be1,
    const float* __restrict__ We2, const float* __restrict__ be2,
    const float* __restrict__ Wp1, const float* __restrict__ bp1,
    const float* __restrict__ Wp2, const float* __restrict__ bp2,
    float* __restrict__ agg, float* __restrict__ dpos, int layer)
{
    __shared__ float sIn[64 * 65];   // staged inputs (dst half, then src half, then m2)
    __shared__ float sM1[64 * 65];   // hidden activations
    __shared__ int   sSrc[64];
    __shared__ int   sDst[64];
    __shared__ float sD2[64];
    __shared__ float sC[64];

    const int t    = threadIdx.x;
    const int w    = t >> 6;
    const int lane = t & 63;
    const int base = blockIdx.x * 64;
    // wave-uniform column offset, forced scalar
    const int wofs = __builtin_amdgcn_readfirstlane(w * 16);

    if (t < 64) {
        sSrc[t] = src[base + t];
        sDst[t] = dst[base + t];
        sD2[t]  = d2[base + t];
        if (POS) sC[t] = bp2[layer];
    }
    __syncthreads();

    // ---- stage x[dst] rows into sIn ----
    #pragma unroll
    for (int i = 0; i < 4; ++i) {
        int e = (t >> 4) + i * 16;
        int c = t & 15;
        const float4 v = *reinterpret_cast<const float4*>(&x[(size_t)sDst[e] * 64 + c * 4]);
        float* p = &sIn[e * 65 + c * 4];
        p[0] = v.x; p[1] = v.y; p[2] = v.z; p[3] = v.w;
    }
    __syncthreads();

    // ---- GEMM1, k = 0..63 (x[dst] part) ----
    float acc[16];
    {
        const float* b = &be1[(size_t)layer * 64 + wofs];
        #pragma unroll
        for (int hh = 0; hh < 16; ++hh) acc[hh] = b[hh];
    }
    const float* W1 = &We1[(size_t)layer * 129 * 64 + wofs];
    for (int k = 0; k < 64; ++k) {
        float inv = sIn[lane * 65 + k];
        const float* wr = W1 + k * 64;
        #pragma unroll
        for (int hh = 0; hh < 16; ++hh) acc[hh] = fmaf(inv, wr[hh], acc[hh]);
    }
    __syncthreads();

    // ---- stage x[src] rows (overwrite sIn) ----
    #pragma unroll
    for (int i = 0; i < 4; ++i) {
        int e = (t >> 4) + i * 16;
        int c = t & 15;
        const float4 v = *reinterpret_cast<const float4*>(&x[(size_t)sSrc[e] * 64 + c * 4]);
        float* p = &sIn[e * 65 + c * 4];
        p[0] = v.x; p[1] = v.y; p[2] = v.z; p[3] = v.w;
    }
    __syncthreads();

    // ---- GEMM1, k = 64..127 (x[src] part) + d2 term ----
    for (int k = 0; k < 64; ++k) {
        float inv = sIn[lane * 65 + k];
        const float* wr = W1 + (64 + k) * 64;
        #pragma unroll
        for (int hh = 0; hh < 16; ++hh) acc[hh] = fmaf(inv, wr[hh], acc[hh]);
    }
    {
        float dv = sD2[lane];
        const float* wr = W1 + 128 * 64;
        #pragma unroll
        for (int hh = 0; hh < 16; ++hh) acc[hh] = fmaf(dv, wr[hh], acc[hh]);
    }
    #pragma unroll
    for (int hh = 0; hh < 16; ++hh) acc[hh] = silu_f(acc[hh]);
    #pragma unroll
    for (int hh = 0; hh < 16; ++hh) sM1[lane * 65 + wofs + hh] = acc[hh];
    __syncthreads();

    // ---- GEMM2 (64 -> 64) ----
    float m2[16];
    {
        const float* b = &be2[(size_t)layer * 64 + wofs];
        #pragma unroll
        for (int hh = 0; hh < 16; ++hh) m2[hh] = b[hh];
    }
    const float* W2 = &We2[(size_t)layer * 64 * 64 + wofs];
    for (int k = 0; k < 64; ++k) {
        float inv = sM1[lane * 65 + k];
        const float* wr = W2 + k * 64;
        #pragma unroll
        for (int hh = 0; hh < 16; ++hh) m2[hh] = fmaf(inv, wr[hh], m2[hh]);
    }
    #pragma unroll
    for (int hh = 0; hh < 16; ++hh) m2[hh] = silu_f(m2[hh]);
    // stash m2 in sIn (sIn reads all completed before previous barrier)
    #pragma unroll
    for (int hh = 0; hh < 16; ++hh) sIn[lane * 65 + wofs + hh] = m2[hh];
    __syncthreads();

    if (POS) {
        // p1 = silu(m2 @ Wp1 + bp1); c = p1 @ Wp2 + bp2  (only last layer matters)
        float p1[16];
        {
            const float* b = &bp1[(size_t)layer * 64 + wofs];
            #pragma unroll
            for (int hh = 0; hh < 16; ++hh) p1[hh] = b[hh];
        }
        const float* P1 = &Wp1[(size_t)layer * 64 * 64 + wofs];
        for (int k = 0; k < 64; ++k) {
            float mv = sIn[lane * 65 + k];
            const float* wr = P1 + k * 64;
            #pragma unroll
            for (int hh = 0; hh < 16; ++hh) p1[hh] = fmaf(mv, wr[hh], p1[hh]);
        }
        float part = 0.0f;
        {
            const float* P2 = &Wp2[(size_t)layer * 64 + wofs];
            #pragma unroll
            for (int hh = 0; hh < 16; ++hh) part += silu_f(p1[hh]) * P2[hh];
        }
        atomicAdd(&sC[lane], part);
        __syncthreads();
        if (w == 0) {
            float c = sC[lane];
            int d = sDst[lane], s = sSrc[lane];
            float rx = pos[3*d+0] - pos[3*s+0];
            float ry = pos[3*d+1] - pos[3*s+1];
            float rz = pos[3*d+2] - pos[3*s+2];
            atomicAdd(&dpos[3*(size_t)d+0], rx * c);
            atomicAdd(&dpos[3*(size_t)d+1], ry * c);
            atomicAdd(&dpos[3*(size_t)d+2], rz * c);
        }
    }

    // ---- scatter m2 into agg (coalesced atomics: 64 lanes = 64 consecutive channels) ----
    #pragma unroll 1
    for (int i = 0; i < 16; ++i) {
        int e = w * 16 + i;
        atomicAdd(&agg[(size_t)sDst[e] * 64 + lane], sIn[e * 65 + lane]);
    }
}

// ---------------- node MLP (tile of 64 nodes per block) ----------------
__global__ __launch_bounds__(256) void egnn_node(
    const float* __restrict__ x, const float* __restrict__ agg,
    const float* __restrict__ Wn1, const float* __restrict__ bn1,
    const float* __restrict__ Wn2, const float* __restrict__ bn2,
    float* __restrict__ xout, int layer)
{
    __shared__ float sX[64 * 65];
    __shared__ float sA[64 * 65];

    const int t    = threadIdx.x;
    const int w    = t >> 6;
    const int lane = t & 63;
    const int base = blockIdx.x * 64;
    const int nval = (NN - base < 64) ? (NN - base) : 64;
    const int wofs = __builtin_amdgcn_readfirstlane(w * 16);

    #pragma unroll
    for (int i = 0; i < 4; ++i) {
        int idx = i * 256 + t;
        int e = idx >> 4, c = idx & 15;
        if (e < nval) {
            const float4 vx = *reinterpret_cast<const float4*>(&x[(size_t)(base + e) * 64 + c * 4]);
            const float4 va = *reinterpret_cast<const float4*>(&agg[(size_t)(base + e) * 64 + c * 4]);
            float* px = &sX[e * 65 + c * 4];
            float* pa = &sA[e * 65 + c * 4];
            px[0]=vx.x; px[1]=vx.y; px[2]=vx.z; px[3]=vx.w;
            pa[0]=va.x; pa[1]=va.y; pa[2]=va.z; pa[3]=va.w;
        }
    }
    __syncthreads();

    float acc[16];
    {
        const float* b = &bn1[(size_t)layer * 64 + wofs];
        #pragma unroll
        for (int hh = 0; hh < 16; ++hh) acc[hh] = b[hh];
    }
    const float* W1 = &Wn1[(size_t)layer * 128 * 64 + wofs];
    for (int k = 0; k < 64; ++k) {
        float inv = sX[lane * 65 + k];
        const float* wr = W1 + k * 64;
        #pragma unroll
        for (int hh = 0; hh < 16; ++hh) acc[hh] = fmaf(inv, wr[hh], acc[hh]);
    }
    for (int k = 0; k < 64; ++k) {
        float inv = sA[lane * 65 + k];
        const float* wr = W1 + (64 + k) * 64;
        #pragma unroll
        for (int hh = 0; hh < 16; ++hh) acc[hh] = fmaf(inv, wr[hh], acc[hh]);
    }
    #pragma unroll
    for (int hh = 0; hh < 16; ++hh) acc[hh] = silu_f(acc[hh]);
    __syncthreads();          // all waves done reading sA
    #pragma unroll
    for (int hh = 0; hh < 16; ++hh) sA[lane * 65 + wofs + hh] = acc[hh];
    __syncthreads();

    float o[16];
    {
        const float* b = &bn2[(size_t)layer * 64 + wofs];
        #pragma unroll
        for (int hh = 0; hh < 16; ++hh) o[hh] = b[hh];
    }
    const float* W2 = &Wn2[(size_t)layer * 64 * 64 + wofs];
    for (int k = 0; k < 64; ++k) {
        float inv = sA[lane * 65 + k];
        const float* wr = W2 + k * 64;
        #pragma unroll
        for (int hh = 0; hh < 16; ++hh) o[hh] = fmaf(inv, wr[hh], o[hh]);
    }
    // stage to sX (all waves long done reading sX) then coalesced store
    #pragma unroll
    for (int hh = 0; hh < 16; ++hh) sX[lane * 65 + wofs + hh] = o[hh];
    __syncthreads();
    #pragma unroll
    for (int i = 0; i < 4; ++i) {
        int idx = i * 256 + t;
        int e = idx >> 4, c = idx & 15;
        if (e < nval) {
            float4 v;
            const float* p = &sX[e * 65 + c * 4];
            v.x = p[0]; v.y = p[1]; v.z = p[2]; v.w = p[3];
            *reinterpret_cast<float4*>(&xout[(size_t)(base + e) * 64 + c * 4]) = v;
        }
    }
}

// ---------------- finalize positions ----------------
__global__ __launch_bounds__(256) void egnn_final(
    const float* __restrict__ pos, const float* __restrict__ dpos,
    const float* __restrict__ deg, const float* __restrict__ logit,
    float* __restrict__ pos_out)
{
    int i = blockIdx.x * 256 + threadIdx.x;
    if (i >= NN * 3) return;
    int node = i / 3;
    float dg = fmaxf(deg[node], 1.0f);
    float sig = 1.0f / (1.0f + __expf(-logit[0]));
    float upd = (dpos[i] / dg) * sig;
    upd = fminf(fmaxf(upd, -5.0f), 5.0f);
    float p = pos[i] + upd;
    pos_out[i] = fminf(fmaxf(p, -500.0f), 500.0f);
}

extern "C" void kernel_launch(void* const* d_in, const int* in_sizes, int n_in,
                              void* d_out, int out_size, void* d_ws, size_t ws_size,
                              hipStream_t stream)
{
    const float* x0    = (const float*)d_in[0];
    const float* pos   = (const float*)d_in[1];
    const int*   src   = (const int*)d_in[2];
    const int*   dst   = src + NE;
    const float* We1   = (const float*)d_in[3];
    const float* be1   = (const float*)d_in[4];
    const float* We2   = (const float*)d_in[5];
    const float* be2   = (const float*)d_in[6];
    const float* Wn1   = (const float*)d_in[7];
    const float* bn1   = (const float*)d_in[8];
    const float* Wn2   = (const float*)d_in[9];
    const float* bn2   = (const float*)d_in[10];
    const float* Wp1   = (const float*)d_in[11];
    const float* bp1   = (const float*)d_in[12];
    const float* Wp2   = (const float*)d_in[13];
    const float* bp2   = (const float*)d_in[14];
    const float* logit = (const float*)d_in[15];

    float* xout    = (float*)d_out;                 // [NN,64]
    float* pos_out = xout + (size_t)NN * 64;        // [NN,3]

    float* ws  = (float*)d_ws;
    float* xA  = ws;  ws += (size_t)NN * 64;
    float* agg = ws;  ws += (size_t)NN * 64;
    float* d2  = ws;  ws += NE;
    float* deg = ws;  ws += NN;
    float* dpos= ws;  ws += (size_t)NN * 3;

    hipMemsetAsync(deg, 0, NN * sizeof(float), stream);
    hipMemsetAsync(dpos, 0, (size_t)NN * 3 * sizeof(float), stream);
    egnn_prep<<<NE / 256, 256, 0, stream>>>(src, dst, pos, d2, deg);

    const float* xin = x0;
    for (int l = 0; l < 4; ++l) {
        hipMemsetAsync(agg, 0, (size_t)NN * 64 * sizeof(float), stream);
        if (l == 3) {
            egnn_edge<true><<<NE / 64, 256, 0, stream>>>(
                xin, d2, src, dst, pos, We1, be1, We2, be2,
                Wp1, bp1, Wp2, bp2, agg, dpos, l);
        } else {
            egnn_edge<false><<<NE / 64, 256, 0, stream>>>(
                xin, d2, src, dst, pos, We1, be1, We2, be2,
                Wp1, bp1, Wp2, bp2, agg, dpos, l);
        }
        float* xo = (l % 2 == 0) ? xA : xout;       // l0->xA, l1->xout, l2->xA, l3->xout
        egnn_node<<<(NN + 63) / 64, 256, 0, stream>>>(xin, agg, Wn1, bn1, Wn2, bn2, xo, l);
        xin = xo;
    }
    egnn_final<<<(NN * 3 + 255) / 256, 256, 0, stream>>>(pos, dpos, deg, logit, pos_out);
}